// Round 10
// baseline (503.623 us; speedup 1.0000x reference)
//
#include <hip/hip_runtime.h>
#include <hip/hip_bf16.h>
#include <hip/hip_cooperative_groups.h>

namespace cg = cooperative_groups;

// ---------------------------------------------------------------------------
// RETAIN forward, MI355X gfx950.
// T=64, B=64, D_IN=4096, E=128, HA=HB=128, D_OUT=4096
// R14: SINGLE cooperative mega-kernel (256 blocks x 512 thr, 1 block/CU):
//      phase 0: grid-strided weight prep (bf16 cast + log2e prefold)
//      grid.sync()
//      phase 1: R13 k_front body (emb GEMM K-split + reduce + gi GEMM)
//      grid.sync()
//      phase 2: R13 k_recur loop (measured best) + R10 fused out-tail
//      Removes 3 launch boundaries + k_out's cold start; stragglers overlap
//      the out-tail. Total LDS ~90KB (1 block/CU by design, grid == #CU).
// ---------------------------------------------------------------------------

typedef __attribute__((ext_vector_type(8))) short short8;
typedef __attribute__((ext_vector_type(4))) float f32x4;
typedef _Float16 half8 __attribute__((ext_vector_type(8)));

#define MFMA16(a, b, c) __builtin_amdgcn_mfma_f32_16x16x32_bf16((a), (b), (c), 0, 0, 0)

#define LOG2E 1.4426950408889634f
#define TLOG2E 2.8853900817779268f

__device__ __forceinline__ unsigned pkbf(float a, float b) {  // v_cvt_pk_bf16_f32
  __hip_bfloat162 t = __float22bfloat162_rn(float2{a, b});
  return *reinterpret_cast<unsigned*>(&t);
}
__device__ __forceinline__ float ex2(float x) { return __builtin_amdgcn_exp2f(x); }
__device__ __forceinline__ float rcpa(float x) { return __builtin_amdgcn_rcpf(x); }
__device__ __forceinline__ float tanh2(float y) {
  float e = ex2(-fmaxf(y, -126.0f));
  return (1.0f - e) * rcpa(1.0f + e);
}

// ---- workspace layout (byte offsets) ----
#define OFF_GI3    16777216u    // 4096*1024 fp16   {ra,za,na,rb,zb,nb,emb,pad}
#define OFF_WEMB   27262976u    // 524288 bf16
#define OFF_WOUT   28311552u    // 524288 bf16
#define OFF_WHHA   29360128u    // 49152 bf16
#define OFF_WHHB   29458432u    // 49152 bf16
#define OFF_WIH    29556736u    // 98304 bf16
#define OFF_WBETA  29753344u    // 16384 bf16

__global__ __launch_bounds__(512) __attribute__((amdgpu_waves_per_eu(2, 2)))
void k_mega(const float* __restrict__ x,
            const float* __restrict__ W_emb, const float* __restrict__ b_emb,
            const float* __restrict__ W_ih_a, const float* __restrict__ W_hh_a,
            const float* __restrict__ b_ih_a, const float* __restrict__ b_hh_a,
            const float* __restrict__ W_ih_b, const float* __restrict__ W_hh_b,
            const float* __restrict__ b_ih_b, const float* __restrict__ b_hh_b,
            const float* __restrict__ w_alpha, const float* __restrict__ b_alpha,
            const float* __restrict__ W_beta, const float* __restrict__ b_beta,
            const float* __restrict__ W_out, const float* __restrict__ b_out,
            float* __restrict__ out, char* __restrict__ ws) {
  const int tid = threadIdx.x, w = tid >> 6, lane = tid & 63, q = lane >> 4, ln = lane & 15;

  unsigned*       wembp  = (unsigned*)(ws + OFF_WEMB);
  unsigned*       woutp  = (unsigned*)(ws + OFF_WOUT);
  unsigned*       whhap  = (unsigned*)(ws + OFF_WHHA);
  unsigned*       whhbp  = (unsigned*)(ws + OFF_WHHB);
  unsigned*       wihp   = (unsigned*)(ws + OFF_WIH);
  unsigned*       wbetap = (unsigned*)(ws + OFF_WBETA);
  _Float16*       gih    = (_Float16*)(ws + OFF_GI3);

  __shared__ float part[8][16][132];          // 67.6 KB; reused as gi stage
  __shared__ unsigned short embs[16][136];    // 4.3 KB
  __shared__ unsigned short hA[2][16 * 136], hB[2][16 * 136];  // 17 KB

  const f32x4 zero = {0.f, 0.f, 0.f, 0.f};

  // ===================== phase 0: weight prep =====================
  {
    const unsigned total = 630784u;
    for (unsigned idx = blockIdx.x * 512u + tid; idx < total; idx += 131072u) {
      unsigned i = idx;
      if (i < 262144u) { float2 v = ((const float2*)W_emb)[i]; wembp[i] = pkbf(v.x, v.y); continue; }
      i -= 262144u;
      if (i < 262144u) { float2 v = ((const float2*)W_out)[i]; woutp[i] = pkbf(v.x, v.y); continue; }
      i -= 262144u;
      if (i < 24576u) {
        float2 v = ((const float2*)W_hh_a)[i];
        const float sc = ((i >> 13) == 2u) ? TLOG2E : LOG2E;
        whhap[i] = pkbf(sc * v.x, sc * v.y); continue;
      }
      i -= 24576u;
      if (i < 24576u) {
        float2 v = ((const float2*)W_hh_b)[i];
        const float sc = ((i >> 13) == 2u) ? TLOG2E : LOG2E;
        whhbp[i] = pkbf(sc * v.x, sc * v.y); continue;
      }
      i -= 24576u;
      if (i < 24576u) {
        float2 v = ((const float2*)W_ih_a)[i];
        const float sc = ((i >> 13) == 2u) ? TLOG2E : LOG2E;
        wihp[i] = pkbf(sc * v.x, sc * v.y); continue;
      }
      i -= 24576u;
      if (i < 24576u) {
        float2 v = ((const float2*)W_ih_b)[i];
        const float sc = ((i >> 13) == 2u) ? TLOG2E : LOG2E;
        wihp[24576u + i] = pkbf(sc * v.x, sc * v.y); continue;
      }
      i -= 24576u;
      { float2 v = ((const float2*)W_beta)[i]; wbetap[i] = pkbf(LOG2E * v.x, LOG2E * v.y); }
    }
  }
  __threadfence();
  cg::this_grid().sync();

  // ===================== phase 1: front (emb + gi) =====================
  {
    const unsigned short* wemb = (const unsigned short*)wembp;
    const unsigned short* wih = (const unsigned short*)wihp;
    const int m0 = blockIdx.x * 16;

    {
      f32x4 acc[8];
#pragma unroll
      for (int nt = 0; nt < 8; ++nt) acc[nt] = zero;

      const float* xp = x + (size_t)(m0 + ln) * 4096 + w * 512 + q * 8;
      const unsigned short* wp = wemb + (size_t)ln * 4096 + w * 512 + q * 8;

#pragma unroll 4
      for (int kk = 0; kk < 16; ++kk) {
        const int ko = kk * 32;
        float4 u0 = *(const float4*)(xp + ko);
        float4 u1 = *(const float4*)(xp + ko + 4);
        union { short8 v; unsigned u[4]; } a0;
        a0.u[0] = pkbf(u0.x, u0.y); a0.u[1] = pkbf(u0.z, u0.w);
        a0.u[2] = pkbf(u1.x, u1.y); a0.u[3] = pkbf(u1.z, u1.w);
#pragma unroll
        for (int nt = 0; nt < 8; ++nt) {
          short8 b = *(const short8*)(wp + (size_t)(nt * 16) * 4096 + ko);
          acc[nt] = MFMA16(a0.v, b, acc[nt]);
        }
      }
#pragma unroll
      for (int nt = 0; nt < 8; ++nt)
#pragma unroll
        for (int r = 0; r < 4; ++r)
          part[w][q * 4 + r][nt * 16 + ln] = acc[nt][r];
    }
    __syncthreads();

    const int rrow = tid & 15, col0 = (tid >> 4) * 4;
    f32x4 sred = *(const f32x4*)(b_emb + col0);
    {
#pragma unroll
      for (int ww = 0; ww < 8; ++ww) {
        const f32x4 v = *(const f32x4*)&part[ww][rrow][col0];
        sred[0] += v[0]; sred[1] += v[1]; sred[2] += v[2]; sred[3] += v[3];
      }
      *(unsigned*)&embs[rrow][col0]     = pkbf(sred[0], sred[1]);
      *(unsigned*)&embs[rrow][col0 + 2] = pkbf(sred[2], sred[3]);
    }
    __syncthreads();

    _Float16* stage = (_Float16*)&part[0][0][0];
#pragma unroll
    for (int j = 0; j < 4; ++j) {
      stage[rrow * 1032 + (col0 + j) * 8 + 6] = (_Float16)sred[j];
      stage[rrow * 1032 + (col0 + j) * 8 + 7] = (_Float16)0.0f;
    }

    {
      short8 af[4];
#pragma unroll
      for (int kc = 0; kc < 4; ++kc)
        af[kc] = *(const short8*)&embs[ln][kc * 32 + q * 8];

      const int nb = w * 96;
      f32x4 acg[6];
#pragma unroll
      for (int nt = 0; nt < 6; ++nt) acg[nt] = zero;

#pragma unroll
      for (int kc = 0; kc < 4; ++kc) {
        const int ko = kc * 32 + q * 8;
#pragma unroll
        for (int nt = 0; nt < 6; ++nt) {
          short8 b = *(const short8*)(wih + (size_t)(nb + nt * 16 + ln) * 128 + ko);
          acg[nt] = MFMA16(af[kc], b, acg[nt]);
        }
      }
#pragma unroll
      for (int nt = 0; nt < 6; ++nt) {
        const int g = nb + nt * 16 + ln;
        const int gg = g >> 7, kout2 = g & 127;
        float bias;
        if (g < 384) bias = b_ih_a[g] + ((gg < 2) ? b_hh_a[g] : 0.0f);
        else {
          const int g2 = g - 384;
          bias = b_ih_b[g2] + ((gg < 5) ? b_hh_b[g2] : 0.0f);
        }
        bias *= (gg == 2 || gg == 5) ? TLOG2E : LOG2E;
#pragma unroll
        for (int r = 0; r < 4; ++r)
          stage[(q * 4 + r) * 1032 + kout2 * 8 + gg] = (_Float16)(acg[nt][r] + bias);
      }
    }
    __syncthreads();

    {
      const int row2 = tid >> 5, seg = tid & 31;
#pragma unroll
      for (int k = 0; k < 4; ++k) {
        const int off = (seg + k * 32) * 8;
        *(short8*)(gih + (size_t)(m0 + row2) * 1024 + off) =
            *(const short8*)(stage + row2 * 1032 + off);
      }
    }
  }
  __threadfence();
  cg::this_grid().sync();

  // ===================== phase 2: recurrence + attention + out =====================
  const unsigned short* whha = (const unsigned short*)whhap;
  const unsigned short* whhb = (const unsigned short*)whhbp;
  const unsigned short* wbeta = (const unsigned short*)wbetap;
  const unsigned short* wout = (const unsigned short*)woutp;

  const int p = blockIdx.x >> 3, btile = blockIdx.x & 7;
  const int i1 = p, i2 = 63 - p;  // i2 >= i1
  const int kout = w * 16 + ln;

  for (int idx = tid; idx < 16 * 136; idx += 512) { hA[0][idx] = 0; hB[0][idx] = 0; }

  const int iq = (q < 2) ? i1 : i2;
  const _Float16* gp[4];
#pragma unroll
  for (int r = 0; r < 4; ++r) {
    const int b = btile * 8 + (q & 1) * 4 + r;
    gp[r] = gih + (size_t)(iq * 64 + b) * 1024 + kout * 8;
  }

  // ---- W_hh B-fragments -> AGPRs (96 regs, pinned)
  short8 fra[3][4], frb[3][4];
#pragma unroll
  for (int g = 0; g < 3; ++g) {
    const unsigned short* ba = whha + (size_t)(g * 128 + kout) * 128;
    const unsigned short* bb = whhb + (size_t)(g * 128 + kout) * 128;
#pragma unroll
    for (int kc = 0; kc < 4; ++kc) {
      fra[g][kc] = *(const short8*)(ba + kc * 32 + q * 8);
      frb[g][kc] = *(const short8*)(bb + kc * 32 + q * 8);
    }
  }
#pragma unroll
  for (int g = 0; g < 3; ++g)
#pragma unroll
    for (int kc = 0; kc < 4; ++kc) {
      asm volatile("" : "+a"(fra[g][kc]));
      asm volatile("" : "+a"(frb[g][kc]));
    }

  // ---- beta B-fragments -> pinned AGPRs
  short8 fbe[4];
#pragma unroll
  for (int kc = 0; kc < 4; ++kc) {
    fbe[kc] = *(const short8*)(wbeta + (size_t)(w * 16 + ln) * 128 + kc * 32 + q * 8);
    asm volatile("" : "+a"(fbe[kc]));
  }

  // ---- alpha B-fragment: replicated all 16 cols
  short8 fal[4];
#pragma unroll
  for (int kc = 0; kc < 4; ++kc) {
    float4 w0 = *(const float4*)(w_alpha + kc * 32 + q * 8);
    float4 w1 = *(const float4*)(w_alpha + kc * 32 + q * 8 + 4);
    union { short8 v; unsigned u[4]; } t;
    t.u[0] = pkbf(0.5f * LOG2E * w0.x, 0.5f * LOG2E * w0.y);
    t.u[1] = pkbf(0.5f * LOG2E * w0.z, 0.5f * LOG2E * w0.w);
    t.u[2] = pkbf(0.5f * LOG2E * w1.x, 0.5f * LOG2E * w1.y);
    t.u[3] = pkbf(0.5f * LOG2E * w1.z, 0.5f * LOG2E * w1.w);
    fal[kc] = t.v;
    asm volatile("" : "+a"(fal[kc]));
  }

  const float bhnA = TLOG2E * b_hh_a[256 + kout];
  const float bhnB = TLOG2E * b_hh_b[256 + kout];
  const float bbet = TLOG2E * b_beta[kout];
  const float bal = LOG2E * b_alpha[0];

  float hRA[4], hRB[4], cac[4], lreg[4], embp[4];
#pragma unroll
  for (int r = 0; r < 4; ++r) { hRA[r] = 0.f; hRB[r] = 0.f; cac[r] = 0.f; lreg[r] = 0.f; embp[r] = 0.f; }

  int jj = iq;
  half8 ngv[4];
#pragma unroll
  for (int r = 0; r < 4; ++r) ngv[r] = *(const half8*)gp[r];

  __syncthreads();

  for (int s = 0; s <= i2; ++s) {
    const int rb = s & 1, wb = rb ^ 1;

    half8 gv[4];
#pragma unroll
    for (int r = 0; r < 4; ++r) gv[r] = ngv[r];

    short8 haf[4], hbf[4];
#pragma unroll
    for (int kc = 0; kc < 4; ++kc) {
      haf[kc] = *(const short8*)(hA[rb] + ln * 136 + kc * 32 + q * 8);
      hbf[kc] = *(const short8*)(hB[rb] + ln * 136 + kc * 32 + q * 8);
    }

    f32x4 accA[3] = {zero, zero, zero}, accB[3] = {zero, zero, zero};
    f32x4 accV = zero, accL = zero;
#pragma unroll
    for (int kc = 0; kc < 4; ++kc) {
#pragma unroll
      for (int g = 0; g < 3; ++g) {
        accA[g] = MFMA16(haf[kc], fra[g][kc], accA[g]);
        accB[g] = MFMA16(hbf[kc], frb[g][kc], accB[g]);
      }
      accV = MFMA16(hbf[kc], fbe[kc], accV);
      accL = MFMA16(haf[kc], fal[kc], accL);
    }

    const bool act = ((unsigned)(s - 1) <= (unsigned)iq);
#pragma unroll
    for (int r = 0; r < 4; ++r) {
      const float logit = accL[r] + bal;
      const float pp = act ? ex2(logit) : 0.0f;
      lreg[r] += pp;
      const float beta = tanh2(accV[r] + bbet);
      cac[r] += pp * beta * embp[r];
    }

#pragma unroll
    for (int r = 0; r < 4; ++r) {
      const int rowoff = (q * 4 + r) * 136 + kout;

      const float erA = ex2(-((float)gv[r][0] + accA[0][r]));
      const float rA = rcpa(1.0f + erA);
      const float tA = (float)gv[r][2] + rA * (accA[2][r] + bhnA);
      const float enA = ex2(-fmaxf(tA, -62.0f));
      const float ezA = ex2(-fmaxf((float)gv[r][1] + accA[1][r], -62.0f));
      const float apnA = 1.0f + enA, apzA = 1.0f + ezA;
      const float numA = fmaf(hRA[r], apnA, ezA * (1.0f - enA));
      const float hnA = numA * rcpa(apnA * apzA);
      hRA[r] = hnA;
      hA[wb][rowoff] = (unsigned short)pkbf(hnA, hnA);

      const float erB = ex2(-((float)gv[r][3] + accB[0][r]));
      const float rB = rcpa(1.0f + erB);
      const float tB = (float)gv[r][5] + rB * (accB[2][r] + bhnB);
      const float enB = ex2(-fmaxf(tB, -62.0f));
      const float ezB = ex2(-fmaxf((float)gv[r][4] + accB[1][r], -62.0f));
      const float apnB = 1.0f + enB, apzB = 1.0f + ezB;
      const float numB = fmaf(hRB[r], apnB, ezB * (1.0f - enB));
      const float hnB = numB * rcpa(apnB * apzB);
      hRB[r] = hnB;
      hB[wb][rowoff] = (unsigned short)pkbf(hnB, hnB);

      embp[r] = (float)gv[r][6];
    }

    if (jj > 0) {
      --jj;
#pragma unroll
      for (int r = 0; r < 4; ++r) gp[r] -= 65536;
    }
#pragma unroll
    for (int r = 0; r < 4; ++r) ngv[r] = *(const half8*)gp[r];

    asm volatile("s_waitcnt lgkmcnt(0)\n\ts_barrier" ::: "memory");
  }

  // ---- epilogue: finalize term i2
  {
    const int rb2 = (i2 + 1) & 1;
    short8 haf[4], hbf[4];
#pragma unroll
    for (int kc = 0; kc < 4; ++kc) {
      haf[kc] = *(const short8*)(hA[rb2] + ln * 136 + kc * 32 + q * 8);
      hbf[kc] = *(const short8*)(hB[rb2] + ln * 136 + kc * 32 + q * 8);
    }
    f32x4 accV = zero, accL = zero;
#pragma unroll
    for (int kc = 0; kc < 4; ++kc) {
      accV = MFMA16(hbf[kc], fbe[kc], accV);
      accL = MFMA16(haf[kc], fal[kc], accL);
    }
    const bool act = (iq == i2);
#pragma unroll
    for (int r = 0; r < 4; ++r) {
      const float logit = accL[r] + bal;
      const float pp = act ? ex2(logit) : 0.0f;
      lreg[r] += pp;
      const float beta = tanh2(accV[r] + bbet);
      cac[r] += pp * beta * embp[r];
    }
  }

  // ---- c rows -> LDS (reuse hA[0]; rows 0..15 = {i1 x 8b, i2 x 8b})
  __syncthreads();
  {
    const int crow0 = (q >= 2 ? 8 : 0) + (q & 1) * 4;
#pragma unroll
    for (int r = 0; r < 4; ++r) {
      const float val = cac[r] * rcpa(lreg[r] * (float)(iq + 1));
      hA[0][(crow0 + r) * 136 + kout] = (unsigned short)pkbf(val, val);
    }
  }
  __syncthreads();

  // ---- out slice: out[m][n] = sigmoid(c[m] . wout[n] + b_out[n])
  {
    short8 cb[4];
#pragma unroll
    for (int kc = 0; kc < 4; ++kc)
      cb[kc] = *(const short8*)(hA[0] + ln * 136 + kc * 32 + q * 8);

    const int m_glob = ((ln >= 8) ? i2 : i1) * 64 + btile * 8 + (ln & 7);
    float* orow = out + (size_t)m_glob * 4096;
    const int nb0 = w * 512;

    for (int nt = 0; nt < 32; ++nt) {
      const int n16 = nb0 + nt * 16;
      f32x4 acc = zero;
#pragma unroll
      for (int kc = 0; kc < 4; ++kc) {
        short8 a = *(const short8*)(wout + (size_t)(n16 + ln) * 128 + kc * 32 + q * 8);
        acc = MFMA16(a, cb[kc], acc);
      }
      const int n0 = n16 + q * 4;
      const float4 bo = *(const float4*)(b_out + n0);
      float4 o;
      o.x = rcpa(1.0f + ex2(-LOG2E * (acc[0] + bo.x)));
      o.y = rcpa(1.0f + ex2(-LOG2E * (acc[1] + bo.y)));
      o.z = rcpa(1.0f + ex2(-LOG2E * (acc[2] + bo.z)));
      o.w = rcpa(1.0f + ex2(-LOG2E * (acc[3] + bo.w)));
      *(float4*)(orow + n0) = o;
    }
  }
}

// ---------------------------------------------------------------------------
extern "C" void kernel_launch(void* const* d_in, const int* in_sizes, int n_in,
                              void* d_out, int out_size, void* d_ws, size_t ws_size,
                              hipStream_t stream) {
  const float* x      = (const float*)d_in[0];
  const float* W_emb  = (const float*)d_in[1];
  const float* b_emb  = (const float*)d_in[2];
  const float* W_ih_a = (const float*)d_in[3];
  const float* W_hh_a = (const float*)d_in[4];
  const float* b_ih_a = (const float*)d_in[5];
  const float* b_hh_a = (const float*)d_in[6];
  const float* W_ih_b = (const float*)d_in[7];
  const float* W_hh_b = (const float*)d_in[8];
  const float* b_ih_b = (const float*)d_in[9];
  const float* b_hh_b = (const float*)d_in[10];
  const float* w_alpha = (const float*)d_in[11];
  const float* b_alpha = (const float*)d_in[12];
  const float* W_beta = (const float*)d_in[13];
  const float* b_beta = (const float*)d_in[14];
  const float* W_out  = (const float*)d_in[15];
  const float* b_out  = (const float*)d_in[16];
  float* out = (float*)d_out;
  char* ws = (char*)d_ws;

  void* args[] = {
      (void*)&x, (void*)&W_emb, (void*)&b_emb, (void*)&W_ih_a, (void*)&W_hh_a,
      (void*)&b_ih_a, (void*)&b_hh_a, (void*)&W_ih_b, (void*)&W_hh_b,
      (void*)&b_ih_b, (void*)&b_hh_b, (void*)&w_alpha, (void*)&b_alpha,
      (void*)&W_beta, (void*)&b_beta, (void*)&W_out, (void*)&b_out,
      (void*)&out, (void*)&ws};

  hipLaunchCooperativeKernel((const void*)k_mega, dim3(256), dim3(512), args, 0,
                             stream);
}

// Round 11
// 323.278 us; speedup vs baseline: 1.5579x; 1.5579x over previous
//
#include <hip/hip_runtime.h>
#include <hip/hip_bf16.h>

// ---------------------------------------------------------------------------
// RETAIN forward, MI355X gfx950.
// T=64, B=64, D_IN=4096, E=128, HA=HB=128, D_OUT=4096
// R15: composite of measured-best pieces (R14 mega reverted; it co-scheduled
//      memory phases at phase-2's 2-waves/SIMD occupancy -> 367us):
//      - k_prep: unchanged.
//      - k_front: R13 form (unroll-4 phase 1, LDS-staged coalesced gih store).
//      - k_recur: R8/R10 loop (measured best 127-128us) + fused out-tail
//        (R10 placement, 326.6us best total) with ONE isolated change:
//        next-nt wout fragments prefetched before current MFMAs.
// ---------------------------------------------------------------------------

typedef __attribute__((ext_vector_type(8))) short short8;
typedef __attribute__((ext_vector_type(4))) float f32x4;
typedef _Float16 half8 __attribute__((ext_vector_type(8)));

#define MFMA16(a, b, c) __builtin_amdgcn_mfma_f32_16x16x32_bf16((a), (b), (c), 0, 0, 0)

#define LOG2E 1.4426950408889634f
#define TLOG2E 2.8853900817779268f

__device__ __forceinline__ unsigned pkbf(float a, float b) {  // v_cvt_pk_bf16_f32
  __hip_bfloat162 t = __float22bfloat162_rn(float2{a, b});
  return *reinterpret_cast<unsigned*>(&t);
}
__device__ __forceinline__ float ex2(float x) { return __builtin_amdgcn_exp2f(x); }
__device__ __forceinline__ float rcpa(float x) { return __builtin_amdgcn_rcpf(x); }
// y is the pre-activation already scaled by 2*log2(e); clamp keeps e finite
__device__ __forceinline__ float tanh2(float y) {
  float e = ex2(-fmaxf(y, -126.0f));
  return (1.0f - e) * rcpa(1.0f + e);
}

// ---- workspace layout (byte offsets) ----
#define OFF_GI3    16777216u    // 4096*1024 fp16   {ra,za,na,rb,zb,nb,emb,pad}
#define OFF_WEMB   27262976u    // 524288 bf16
#define OFF_WOUT   28311552u    // 524288 bf16
#define OFF_WHHA   29360128u    // 49152 bf16       (r,z rows *log2e; n rows *2log2e)
#define OFF_WHHB   29458432u    // 49152 bf16
#define OFF_WIH    29556736u    // 98304 bf16       [W_ih_a ; W_ih_b], gate-scaled
#define OFF_WBETA  29753344u    // 16384 bf16       log2e * W_beta  (0.5 * 2log2e)

// ---------------------------------------------------------------------------
// pair-wise weight cast + activation-scale prefold (all section bounds even)
__global__ void k_prep(const float* W_emb, const float* W_out,
                       const float* W_hh_a, const float* W_hh_b,
                       const float* W_ih_a, const float* W_ih_b,
                       const float* W_beta,
                       unsigned* wemb, unsigned* wout,
                       unsigned* whha, unsigned* whhb,
                       unsigned* wih, unsigned* wbeta) {
  const unsigned total = 630784u;  // element-pairs
  for (unsigned idx = blockIdx.x * 256u + threadIdx.x; idx < total;
       idx += gridDim.x * 256u) {
    unsigned i = idx;
    if (i < 262144u) { float2 v = ((const float2*)W_emb)[i]; wemb[i] = pkbf(v.x, v.y); continue; }
    i -= 262144u;
    if (i < 262144u) { float2 v = ((const float2*)W_out)[i]; wout[i] = pkbf(v.x, v.y); continue; }
    i -= 262144u;
    // gate rows: pair i -> element row (2i)/128 = i>>6; gate = row>>7 = i>>13
    if (i < 24576u) {
      float2 v = ((const float2*)W_hh_a)[i];
      const float sc = ((i >> 13) == 2u) ? TLOG2E : LOG2E;
      whha[i] = pkbf(sc * v.x, sc * v.y); continue;
    }
    i -= 24576u;
    if (i < 24576u) {
      float2 v = ((const float2*)W_hh_b)[i];
      const float sc = ((i >> 13) == 2u) ? TLOG2E : LOG2E;
      whhb[i] = pkbf(sc * v.x, sc * v.y); continue;
    }
    i -= 24576u;
    if (i < 24576u) {
      float2 v = ((const float2*)W_ih_a)[i];
      const float sc = ((i >> 13) == 2u) ? TLOG2E : LOG2E;
      wih[i] = pkbf(sc * v.x, sc * v.y); continue;
    }
    i -= 24576u;
    if (i < 24576u) {
      float2 v = ((const float2*)W_ih_b)[i];
      const float sc = ((i >> 13) == 2u) ? TLOG2E : LOG2E;
      wih[24576u + i] = pkbf(sc * v.x, sc * v.y); continue;
    }
    i -= 24576u;
    { float2 v = ((const float2*)W_beta)[i]; wbeta[i] = pkbf(LOG2E * v.x, LOG2E * v.y); }
  }
}

// ---------------------------------------------------------------------------
// Fused front-end: emb = x @ W_emb^T + b_emb, then gi = emb @ W_ih^T + biases.
// 256 blocks x 512 thr; block owns 16 rows. Phase-1: unroll-4 direct loads.
__global__ __launch_bounds__(512) void k_front(const float* __restrict__ x,
                                               const unsigned short* __restrict__ wemb,
                                               const unsigned short* __restrict__ wih,
                                               const float* __restrict__ b_emb,
                                               const float* __restrict__ b_ih_a,
                                               const float* __restrict__ b_ih_b,
                                               const float* __restrict__ b_hh_a,
                                               const float* __restrict__ b_hh_b,
                                               _Float16* __restrict__ gih) {
  const int tid = threadIdx.x, w = tid >> 6, lane = tid & 63, q = lane >> 4, ln = lane & 15;
  const int m0 = blockIdx.x * 16;

  __shared__ float part[8][16][132];          // 67.6 KB; reused as gi stage
  __shared__ unsigned short embs[16][136];    // 4.3 KB bf16 emb tile

  const f32x4 zero = {0.f, 0.f, 0.f, 0.f};

  // ---- phase 1: emb partial for this wave's K-chunk
  {
    f32x4 acc[8];
#pragma unroll
    for (int nt = 0; nt < 8; ++nt) acc[nt] = zero;

    const float* xp = x + (size_t)(m0 + ln) * 4096 + w * 512 + q * 8;
    const unsigned short* wp = wemb + (size_t)ln * 4096 + w * 512 + q * 8;

#pragma unroll 4
    for (int kk = 0; kk < 16; ++kk) {
      const int ko = kk * 32;
      float4 u0 = *(const float4*)(xp + ko);
      float4 u1 = *(const float4*)(xp + ko + 4);
      union { short8 v; unsigned u[4]; } a0;
      a0.u[0] = pkbf(u0.x, u0.y); a0.u[1] = pkbf(u0.z, u0.w);
      a0.u[2] = pkbf(u1.x, u1.y); a0.u[3] = pkbf(u1.z, u1.w);
#pragma unroll
      for (int nt = 0; nt < 8; ++nt) {
        short8 b = *(const short8*)(wp + (size_t)(nt * 16) * 4096 + ko);
        acc[nt] = MFMA16(a0.v, b, acc[nt]);
      }
    }
#pragma unroll
    for (int nt = 0; nt < 8; ++nt)
#pragma unroll
      for (int r = 0; r < 4; ++r)
        part[w][q * 4 + r][nt * 16 + ln] = acc[nt][r];
  }
  __syncthreads();

  // ---- cross-wave reduce into registers; emb bf16 -> embs
  const int rrow = tid & 15, col0 = (tid >> 4) * 4;
  f32x4 sred = *(const f32x4*)(b_emb + col0);
  {
#pragma unroll
    for (int ww = 0; ww < 8; ++ww) {
      const f32x4 v = *(const f32x4*)&part[ww][rrow][col0];
      sred[0] += v[0]; sred[1] += v[1]; sred[2] += v[2]; sred[3] += v[3];
    }
    *(unsigned*)&embs[rrow][col0]     = pkbf(sred[0], sred[1]);
    *(unsigned*)&embs[rrow][col0 + 2] = pkbf(sred[2], sred[3]);
  }
  __syncthreads();   // all part f32 reads done -> safe to reuse as stage

  // ---- stage = fp16 [16][1032] over the part buffer
  _Float16* stage = (_Float16*)&part[0][0][0];

#pragma unroll
  for (int j = 0; j < 4; ++j) {
    stage[rrow * 1032 + (col0 + j) * 8 + 6] = (_Float16)sred[j];
    stage[rrow * 1032 + (col0 + j) * 8 + 7] = (_Float16)0.0f;
  }

  // ---- phase 2: gi for cols [w*96, w*96+96) -> stage
  {
    short8 af[4];
#pragma unroll
    for (int kc = 0; kc < 4; ++kc)
      af[kc] = *(const short8*)&embs[ln][kc * 32 + q * 8];

    const int nb = w * 96;
    f32x4 acg[6];
#pragma unroll
    for (int nt = 0; nt < 6; ++nt) acg[nt] = zero;

#pragma unroll
    for (int kc = 0; kc < 4; ++kc) {
      const int ko = kc * 32 + q * 8;
#pragma unroll
      for (int nt = 0; nt < 6; ++nt) {
        short8 b = *(const short8*)(wih + (size_t)(nb + nt * 16 + ln) * 128 + ko);
        acg[nt] = MFMA16(af[kc], b, acg[nt]);
      }
    }
#pragma unroll
    for (int nt = 0; nt < 6; ++nt) {
      const int g = nb + nt * 16 + ln;
      const int gg = g >> 7, kout = g & 127;
      float bias;
      if (g < 384) bias = b_ih_a[g] + ((gg < 2) ? b_hh_a[g] : 0.0f);
      else {
        const int g2 = g - 384;
        bias = b_ih_b[g2] + ((gg < 5) ? b_hh_b[g2] : 0.0f);
      }
      bias *= (gg == 2 || gg == 5) ? TLOG2E : LOG2E;
#pragma unroll
      for (int r = 0; r < 4; ++r)
        stage[(q * 4 + r) * 1032 + kout * 8 + gg] = (_Float16)(acg[nt][r] + bias);
    }
  }
  __syncthreads();

  // ---- coalesced stage -> gih: 16 rows x 1024 halves, dwordx4 per store
  {
    const int row2 = tid >> 5, seg = tid & 31;
#pragma unroll
    for (int k = 0; k < 4; ++k) {
      const int off = (seg + k * 32) * 8;
      *(short8*)(gih + (size_t)(m0 + row2) * 1024 + off) =
          *(const short8*)(stage + row2 * 1032 + off);
    }
  }
}

// ---------------------------------------------------------------------------
// Fused recurrence + attention + OUT-GEMM slice (R10 placement).
// 256 blocks x 512 thr. Loop byte-identical to R8/R13 measured best.
__global__ __launch_bounds__(512) __attribute__((amdgpu_waves_per_eu(2, 2)))
void k_recur(const _Float16* __restrict__ gih,
             const unsigned short* __restrict__ whha, const unsigned short* __restrict__ whhb,
             const unsigned short* __restrict__ wbeta,
             const float* __restrict__ b_hh_a, const float* __restrict__ b_hh_b,
             const float* __restrict__ b_beta, const float* __restrict__ b_alpha,
             const float* __restrict__ w_alpha,
             const unsigned short* __restrict__ wout,
             const float* __restrict__ b_out,
             float* __restrict__ out) {
  const int tid = threadIdx.x, w = tid >> 6, lane = tid & 63, q = lane >> 4, ln = lane & 15;
  const int p = blockIdx.x >> 3, btile = blockIdx.x & 7;
  const int i1 = p, i2 = 63 - p;  // i2 >= i1
  const int kout = w * 16 + ln;

  __shared__ unsigned short hA[2][16 * 136], hB[2][16 * 136];

  for (int idx = tid; idx < 16 * 136; idx += 512) { hA[0][idx] = 0; hB[0][idx] = 0; }

  const int iq = (q < 2) ? i1 : i2;
  const _Float16* gp[4];
#pragma unroll
  for (int r = 0; r < 4; ++r) {
    const int b = btile * 8 + (q & 1) * 4 + r;
    gp[r] = gih + (size_t)(iq * 64 + b) * 1024 + kout * 8;
  }

  // ---- W_hh B-fragments -> AGPRs (96 regs, pinned)
  short8 fra[3][4], frb[3][4];
#pragma unroll
  for (int g = 0; g < 3; ++g) {
    const unsigned short* ba = whha + (size_t)(g * 128 + kout) * 128;
    const unsigned short* bb = whhb + (size_t)(g * 128 + kout) * 128;
#pragma unroll
    for (int kc = 0; kc < 4; ++kc) {
      fra[g][kc] = *(const short8*)(ba + kc * 32 + q * 8);
      frb[g][kc] = *(const short8*)(bb + kc * 32 + q * 8);
    }
  }
#pragma unroll
  for (int g = 0; g < 3; ++g)
#pragma unroll
    for (int kc = 0; kc < 4; ++kc) {
      asm volatile("" : "+a"(fra[g][kc]));
      asm volatile("" : "+a"(frb[g][kc]));
    }

  // ---- beta B-fragments (loop-invariant) -> pinned AGPRs (16 regs)
  short8 fbe[4];
#pragma unroll
  for (int kc = 0; kc < 4; ++kc) {
    fbe[kc] = *(const short8*)(wbeta + (size_t)(w * 16 + ln) * 128 + kc * 32 + q * 8);
    asm volatile("" : "+a"(fbe[kc]));
  }

  // ---- alpha B-fragment: SAME 0.5*log2e*w_alpha in ALL 16 cols -> accL[r]
  // holds the logit for row q*4+r in EVERY lane (no broadcast needed).
  short8 fal[4];
#pragma unroll
  for (int kc = 0; kc < 4; ++kc) {
    float4 w0 = *(const float4*)(w_alpha + kc * 32 + q * 8);
    float4 w1 = *(const float4*)(w_alpha + kc * 32 + q * 8 + 4);
    union { short8 v; unsigned u[4]; } t;
    t.u[0] = pkbf(0.5f * LOG2E * w0.x, 0.5f * LOG2E * w0.y);
    t.u[1] = pkbf(0.5f * LOG2E * w0.z, 0.5f * LOG2E * w0.w);
    t.u[2] = pkbf(0.5f * LOG2E * w1.x, 0.5f * LOG2E * w1.y);
    t.u[3] = pkbf(0.5f * LOG2E * w1.z, 0.5f * LOG2E * w1.w);
    fal[kc] = t.v;
    asm volatile("" : "+a"(fal[kc]));
  }

  const float bhnA = TLOG2E * b_hh_a[256 + kout];
  const float bhnB = TLOG2E * b_hh_b[256 + kout];
  const float bbet = TLOG2E * b_beta[kout];
  const float bal = LOG2E * b_alpha[0];

  float hRA[4], hRB[4], cac[4], lreg[4], embp[4];
#pragma unroll
  for (int r = 0; r < 4; ++r) { hRA[r] = 0.f; hRB[r] = 0.f; cac[r] = 0.f; lreg[r] = 0.f; embp[r] = 0.f; }

  const f32x4 zero = {0.f, 0.f, 0.f, 0.f};
  int jj = iq;
  half8 ngv[4];
#pragma unroll
  for (int r = 0; r < 4; ++r) ngv[r] = *(const half8*)gp[r];

  __syncthreads();

  for (int s = 0; s <= i2; ++s) {
    const int rb = s & 1, wb = rb ^ 1;

    half8 gv[4];
#pragma unroll
    for (int r = 0; r < 4; ++r) gv[r] = ngv[r];

    // ---- h_s A-fragments (read ONCE; feed gates + beta + alpha)
    short8 haf[4], hbf[4];
#pragma unroll
    for (int kc = 0; kc < 4; ++kc) {
      haf[kc] = *(const short8*)(hA[rb] + ln * 136 + kc * 32 + q * 8);
      hbf[kc] = *(const short8*)(hB[rb] + ln * 136 + kc * 32 + q * 8);
    }

    // ---- MFMA clump: 24 gates + 4 beta + 4 alpha
    f32x4 accA[3] = {zero, zero, zero}, accB[3] = {zero, zero, zero};
    f32x4 accV = zero, accL = zero;
#pragma unroll
    for (int kc = 0; kc < 4; ++kc) {
#pragma unroll
      for (int g = 0; g < 3; ++g) {
        accA[g] = MFMA16(haf[kc], fra[g][kc], accA[g]);
        accB[g] = MFMA16(hbf[kc], frb[g][kc], accB[g]);
      }
      accV = MFMA16(hbf[kc], fbe[kc], accV);
      accL = MFMA16(haf[kc], fal[kc], accL);
    }

    // ---- finalize attention term s-1 (uses h_s): pp, beta, emb from s-1
    const bool act = ((unsigned)(s - 1) <= (unsigned)iq);
#pragma unroll
    for (int r = 0; r < 4; ++r) {
      const float logit = accL[r] + bal;               // same in every lane
      const float pp = act ? ex2(logit) : 0.0f;
      lreg[r] += pp;
      const float beta = tanh2(accV[r] + bbet);
      cac[r] += pp * beta * embp[r];
    }

    // ---- gate math -> h_{s+1}, write to buf wb (merged single-rcp combine)
#pragma unroll
    for (int r = 0; r < 4; ++r) {
      const int rowoff = (q * 4 + r) * 136 + kout;

      const float erA = ex2(-((float)gv[r][0] + accA[0][r]));
      const float rA = rcpa(1.0f + erA);
      const float tA = (float)gv[r][2] + rA * (accA[2][r] + bhnA);
      const float enA = ex2(-fmaxf(tA, -62.0f));
      const float ezA = ex2(-fmaxf((float)gv[r][1] + accA[1][r], -62.0f));
      const float apnA = 1.0f + enA, apzA = 1.0f + ezA;
      const float numA = fmaf(hRA[r], apnA, ezA * (1.0f - enA));
      const float hnA = numA * rcpa(apnA * apzA);
      hRA[r] = hnA;
      hA[wb][rowoff] = (unsigned short)pkbf(hnA, hnA);

      const float erB = ex2(-((float)gv[r][3] + accB[0][r]));
      const float rB = rcpa(1.0f + erB);
      const float tB = (float)gv[r][5] + rB * (accB[2][r] + bhnB);
      const float enB = ex2(-fmaxf(tB, -62.0f));
      const float ezB = ex2(-fmaxf((float)gv[r][4] + accB[1][r], -62.0f));
      const float apnB = 1.0f + enB, apzB = 1.0f + ezB;
      const float numB = fmaf(hRB[r], apnB, ezB * (1.0f - enB));
      const float hnB = numB * rcpa(apnB * apzB);
      hRB[r] = hnB;
      hB[wb][rowoff] = (unsigned short)pkbf(hnB, hnB);

      embp[r] = (float)gv[r][6];
    }

    // ---- advance + prefetch s+1 (stays in flight across the raw barrier)
    if (jj > 0) {
      --jj;
#pragma unroll
      for (int r = 0; r < 4; ++r) gp[r] -= 65536;  // 64 rows * 1024 halves
    }
#pragma unroll
    for (int r = 0; r < 4; ++r) ngv[r] = *(const half8*)gp[r];

    // raw barrier: drain LDS only; global prefetch loads stay outstanding
    asm volatile("s_waitcnt lgkmcnt(0)\n\ts_barrier" ::: "memory");
  }

  // ---- epilogue: finalize term i2 (active only for rows with iq == i2)
  {
    const int rb2 = (i2 + 1) & 1;
    short8 haf[4], hbf[4];
#pragma unroll
    for (int kc = 0; kc < 4; ++kc) {
      haf[kc] = *(const short8*)(hA[rb2] + ln * 136 + kc * 32 + q * 8);
      hbf[kc] = *(const short8*)(hB[rb2] + ln * 136 + kc * 32 + q * 8);
    }
    f32x4 accV = zero, accL = zero;
#pragma unroll
    for (int kc = 0; kc < 4; ++kc) {
      accV = MFMA16(hbf[kc], fbe[kc], accV);
      accL = MFMA16(haf[kc], fal[kc], accL);
    }
    const bool act = (iq == i2);
#pragma unroll
    for (int r = 0; r < 4; ++r) {
      const float logit = accL[r] + bal;
      const float pp = act ? ex2(logit) : 0.0f;
      lreg[r] += pp;
      const float beta = tanh2(accV[r] + bbet);
      cac[r] += pp * beta * embp[r];
    }
  }

  // ---- c rows -> LDS (reuse hA[0]; rows 0..15 = {i1 x 8b, i2 x 8b})
  __syncthreads();   // everyone done reading h buffers
  {
    const int crow0 = (q >= 2 ? 8 : 0) + (q & 1) * 4;
#pragma unroll
    for (int r = 0; r < 4; ++r) {
      const float val = cac[r] * rcpa(lreg[r] * (float)(iq + 1));
      hA[0][(crow0 + r) * 136 + kout] = (unsigned short)pkbf(val, val);
    }
  }
  __syncthreads();

  // ---- out slice: out[m][n] = sigmoid(c[m] . wout[n] + b_out[n])
  // Swapped operands: A = wout rows (n), B = c rows (m, from LDS).
  // ONE isolated change vs R10: next-nt wout fragments prefetched before
  // the current MFMAs (cross-iteration L2-latency overlap).
  {
    short8 cb[4];
#pragma unroll
    for (int kc = 0; kc < 4; ++kc)
      cb[kc] = *(const short8*)(hA[0] + ln * 136 + kc * 32 + q * 8);

    const int m_glob = ((ln >= 8) ? i2 : i1) * 64 + btile * 8 + (ln & 7);
    float* orow = out + (size_t)m_glob * 4096;
    const int nb0 = w * 512;
    const unsigned short* wbase = wout + (size_t)(nb0 + ln) * 128 + q * 8;

    short8 acur[4], anxt[4];
#pragma unroll
    for (int kc = 0; kc < 4; ++kc) acur[kc] = *(const short8*)(wbase + kc * 32);

    for (int nt = 0; nt < 32; ++nt) {
      if (nt < 31) {
#pragma unroll
        for (int kc = 0; kc < 4; ++kc)
          anxt[kc] = *(const short8*)(wbase + (size_t)(nt + 1) * 2048 + kc * 32);
      }
      f32x4 acc = zero;
#pragma unroll
      for (int kc = 0; kc < 4; ++kc) acc = MFMA16(acur[kc], cb[kc], acc);

      const int n0 = nb0 + nt * 16 + q * 4;
      const float4 bo = *(const float4*)(b_out + n0);
      float4 o;
      o.x = rcpa(1.0f + ex2(-LOG2E * (acc[0] + bo.x)));
      o.y = rcpa(1.0f + ex2(-LOG2E * (acc[1] + bo.y)));
      o.z = rcpa(1.0f + ex2(-LOG2E * (acc[2] + bo.z)));
      o.w = rcpa(1.0f + ex2(-LOG2E * (acc[3] + bo.w)));
      *(float4*)(orow + n0) = o;

#pragma unroll
      for (int kc = 0; kc < 4; ++kc) acur[kc] = anxt[kc];
    }
  }
}

// ---------------------------------------------------------------------------
extern "C" void kernel_launch(void* const* d_in, const int* in_sizes, int n_in,
                              void* d_out, int out_size, void* d_ws, size_t ws_size,
                              hipStream_t stream) {
  const float* x      = (const float*)d_in[0];
  const float* W_emb  = (const float*)d_in[1];
  const float* b_emb  = (const float*)d_in[2];
  const float* W_ih_a = (const float*)d_in[3];
  const float* W_hh_a = (const float*)d_in[4];
  const float* b_ih_a = (const float*)d_in[5];
  const float* b_hh_a = (const float*)d_in[6];
  const float* W_ih_b = (const float*)d_in[7];
  const float* W_hh_b = (const float*)d_in[8];
  const float* b_ih_b = (const float*)d_in[9];
  const float* b_hh_b = (const float*)d_in[10];
  const float* w_alpha = (const float*)d_in[11];
  const float* b_alpha = (const float*)d_in[12];
  const float* W_beta = (const float*)d_in[13];
  const float* b_beta = (const float*)d_in[14];
  const float* W_out  = (const float*)d_in[15];
  const float* b_out  = (const float*)d_in[16];
  float* out = (float*)d_out;

  char* ws = (char*)d_ws;
  _Float16*       gih    = (_Float16*)(ws + OFF_GI3);
  unsigned*       wemb   = (unsigned*)(ws + OFF_WEMB);
  unsigned*       wout   = (unsigned*)(ws + OFF_WOUT);
  unsigned*       whha   = (unsigned*)(ws + OFF_WHHA);
  unsigned*       whhb   = (unsigned*)(ws + OFF_WHHB);
  unsigned*       wih    = (unsigned*)(ws + OFF_WIH);
  unsigned*       wbeta  = (unsigned*)(ws + OFF_WBETA);

  k_prep<<<1024, 256, 0, stream>>>(W_emb, W_out, W_hh_a, W_hh_b, W_ih_a, W_ih_b,
                                   W_beta, wemb, wout, whha, whhb, wih, wbeta);
  k_front<<<256, 512, 0, stream>>>(x, (const unsigned short*)wemb,
                                   (const unsigned short*)wih, b_emb,
                                   b_ih_a, b_ih_b, b_hh_a, b_hh_b, gih);
  k_recur<<<256, 512, 0, stream>>>(gih, (const unsigned short*)whha,
                                   (const unsigned short*)whhb, (const unsigned short*)wbeta,
                                   b_hh_a, b_hh_b, b_beta, b_alpha, w_alpha,
                                   (const unsigned short*)wout, b_out, out);
}